// Round 4
// baseline (594.398 us; speedup 1.0000x reference)
//
#include <hip/hip_runtime.h>
#include <hip/hip_bf16.h>

typedef __attribute__((ext_vector_type(4))) float f32x4;
typedef __attribute__((ext_vector_type(8))) short s16x8;
typedef __attribute__((ext_vector_type(4))) unsigned short u16x4;

#define B_      32
#define S_      128
#define SEQ     129
#define IN_DIM  1024
#define HD      1024
#define NHEAD   8
#define DH      128
#define OUT_DIM 256
#define KC      10
#define DFF     2048
#define MROWS   (B_*SEQ)     // 4128
#define MPAD    4224         // 33 * 128
#define NCAND   (B_*S_*KC)   // 40960 = 320*128

__device__ __forceinline__ short f2bf(float f) {
  unsigned u = __builtin_bit_cast(unsigned, f);
  u += 0x7FFFu + ((u >> 16) & 1u);   // RNE to bf16
  return (short)(u >> 16);
}
__device__ __forceinline__ float bf2f(short s) {
  return __builtin_bit_cast(float, ((unsigned)(unsigned short)s) << 16);
}
__device__ __forceinline__ void gload16(const short* g, short* l) {
  __builtin_amdgcn_global_load_lds(
      (const __attribute__((address_space(1))) unsigned*)g,
      (__attribute__((address_space(3))) unsigned*)l, 16, 0, 0);
}

// ---------------- ALL weight transposes fused: W[K][N] f32 -> Wt[N][K] bf16 --
__global__ __launch_bounds__(256) void transpose_all(
    const float* __restrict__ W_in,  const float* __restrict__ Wqkv,
    const float* __restrict__ Wo,    const float* __restrict__ W1,
    const float* __restrict__ W2,    const float* __restrict__ W_out,
    const float* __restrict__ dsW1,
    short* __restrict__ WinT,  short* __restrict__ WqkvT,
    short* __restrict__ WoT,   short* __restrict__ W1T,
    short* __restrict__ W2T,   short* __restrict__ WoutT,
    short* __restrict__ dsW1T) {
  const int b = blockIdx.x;
  const float* src; short* dst; int K, N, local;
  if (b < 1024)       { src = W_in;  dst = WinT;  K = 1024; N = 1024; local = b; }
  else if (b < 7168)  { int l = (b - 1024) / 3072; local = (b - 1024) % 3072;
                        src = Wqkv + (size_t)l * 1024 * 3072;
                        dst = WqkvT + (size_t)l * 3072 * 1024; K = 1024; N = 3072; }
  else if (b < 9216)  { int l = (b - 7168) / 1024; local = (b - 7168) % 1024;
                        src = Wo + (size_t)l * 1024 * 1024;
                        dst = WoT + (size_t)l * 1024 * 1024; K = 1024; N = 1024; }
  else if (b < 13312) { int l = (b - 9216) / 2048; local = (b - 9216) % 2048;
                        src = W1 + (size_t)l * 1024 * 2048;
                        dst = W1T + (size_t)l * 2048 * 1024; K = 1024; N = 2048; }
  else if (b < 17408) { int l = (b - 13312) / 2048; local = (b - 13312) % 2048;
                        src = W2 + (size_t)l * 2048 * 1024;
                        dst = W2T + (size_t)l * 1024 * 2048; K = 2048; N = 1024; }
  else if (b < 17664) { local = b - 17408; src = W_out; dst = WoutT; K = 1024; N = 256; }
  else                { local = b - 17664; src = dsW1;  dst = dsW1T; K = 256;  N = 256; }
  const int tilesX = N >> 5;
  const int n0 = (local % tilesX) << 5, k0 = (local / tilesX) << 5;

  __shared__ float tile[32][33];
  const int tx = threadIdx.x & 31, ty = threadIdx.x >> 5;  // 32 x 8
#pragma unroll
  for (int i = 0; i < 4; ++i)
    tile[ty + i * 8][tx] = src[(size_t)(k0 + ty + i * 8) * N + n0 + tx];
  __syncthreads();
#pragma unroll
  for (int i = 0; i < 4; ++i)
    dst[(size_t)(n0 + ty + i * 8) * K + k0 + tx] = f2bf(tile[tx][ty + i * 8]);
}

// ---------------- GEMM: C[M][N] = A[M][K](bf16) * Bt[N][K](bf16) + bias ------
// 3-deep pipelined: counted s_waitcnt vmcnt(8) (never 0 in-loop), raw
// s_barrier, 6 LDS buffers. XCD-chunked (m204 bijective) + GROUP_M tile order
// for per-XCD L2 reuse. A rows [bm,bm+128) readable (M padded). N%128==0,
// K%64==0, K>=96.
template <int EPI, typename OutT>
__global__ __launch_bounds__(256) void gemm_bt(const short* __restrict__ A,
                                               const short* __restrict__ Bt,
                                               const float* __restrict__ bias,
                                               OutT* __restrict__ C,
                                               int M, int N, int K,
                                               int gm, int gn, int groupM) {
  __shared__ alignas(16) short As0[4096], As1[4096], As2[4096];
  __shared__ alignas(16) short Bs0[4096], Bs1[4096], Bs2[4096];
  const int tid = threadIdx.x;
  const int lane = tid & 63, wave = tid >> 6;
  const int wr = wave >> 1, wc = wave & 1;          // 2x2 waves, 64x64 each

  // --- XCD-chunked bijective remap (m204) + grouped tile order --------------
  const int nwg = gm * gn;
  const int orig = blockIdx.x;
  const int xcd = orig & 7, kk = orig >> 3;
  const int q = nwg >> 3, r = nwg & 7;
  const int wg = (xcd < r ? xcd * (q + 1) : r * (q + 1) + (xcd - r) * q) + kk;
  const int tpg = groupM * gn;
  const int grp = wg / tpg, rem = wg % tpg;
  const int g0 = grp * groupM;
  const int gsz = (groupM < gm - g0) ? groupM : (gm - g0);
  const int bm = (g0 + rem % gsz) * 128;
  const int bn = (rem / gsz) * 128;

  // staging: pre-swizzled global source, linear LDS dest (global_load_lds).
  // slot idx = i*256 + tid; row r = idx>>2; lds 16B-slot s = idx&3;
  // global 16B-slot g = s ^ ((r>>1)&3)
  const short* pa[2];
  const short* pb[2];
#pragma unroll
  for (int i = 0; i < 2; ++i) {
    const int idx = i * 256 + tid;
    const int rr = idx >> 2, ss = idx & 3, gg = ss ^ ((rr >> 1) & 3);
    pa[i] = A + (size_t)(bm + rr) * K + gg * 8;
    pb[i] = Bt + (size_t)(bn + rr) * K + gg * 8;
  }

  auto stage = [&](short* aBuf, short* bBuf, int tile) {
    const int kofs = tile << 5;
    gload16(pa[0] + kofs, aBuf + wave * 512);
    gload16(pa[1] + kofs, aBuf + 2048 + wave * 512);
    gload16(pb[0] + kofs, bBuf + wave * 512);
    gload16(pb[1] + kofs, bBuf + 2048 + wave * 512);
  };

  // fragment reads (swizzled): row rr, k-slot ks -> shorts rr*32 + ((ks^sx)<<3)
  const int lrow = lane & 15, ks = lane >> 4;
  const int sx = (lrow >> 1) & 3;
  const int koff = ((ks ^ sx) << 3);

  f32x4 acc[4][4] = {};

  auto compute = [&](const short* as, const short* bs) {
    s16x8 af[4], bfr[4];
#pragma unroll
    for (int m = 0; m < 4; ++m)
      af[m] = *(const s16x8*)&as[(wr * 64 + m * 16 + lrow) * 32 + koff];
#pragma unroll
    for (int n = 0; n < 4; ++n)
      bfr[n] = *(const s16x8*)&bs[(wc * 64 + n * 16 + lrow) * 32 + koff];
#pragma unroll
    for (int m = 0; m < 4; ++m)
#pragma unroll
      for (int n = 0; n < 4; ++n)
        asm("v_mfma_f32_16x16x32_bf16 %0, %1, %2, %0"
            : "+v"(acc[m][n]) : "v"(af[m]), "v"(bfr[n]));
  };

  const int NT = K >> 5;                 // >= 8 at all call sites
  stage(As0, Bs0, 0);
  stage(As1, Bs1, 1);
  stage(As2, Bs2, 2);                    // vm = 12
  asm volatile("s_waitcnt vmcnt(8)" ::: "memory");   // tile 0 landed
  __builtin_amdgcn_s_barrier();

#define PHASE(bufA, bufB, tcur, tnext)                                   \
  if ((tcur) < NT) compute(bufA, bufB);                                  \
  __builtin_amdgcn_s_barrier();        /* all waves done reading buf */  \
  stage(bufA, bufB, (tnext) < NT ? (tnext) : NT - 1);                    \
  asm volatile("s_waitcnt vmcnt(8)" ::: "memory"); /* next tile ready */ \
  __builtin_amdgcn_s_barrier();

  for (int t = 0; t < NT; t += 3) {
    PHASE(As0, Bs0, t,     t + 3)
    PHASE(As1, Bs1, t + 1, t + 4)
    PHASE(As2, Bs2, t + 2, t + 5)
  }
#undef PHASE
  asm volatile("s_waitcnt vmcnt(0)" ::: "memory");   // drain before LDS dies

  const int lg4 = ks << 2;
#pragma unroll
  for (int n = 0; n < 4; ++n) {
    const int col = bn + wc * 64 + n * 16 + lrow;
    const float bv = bias[col];
#pragma unroll
    for (int m = 0; m < 4; ++m) {
#pragma unroll
      for (int r2 = 0; r2 < 4; ++r2) {
        const int row = bm + wr * 64 + m * 16 + lg4 + r2;
        if (row < M) {
          float v = acc[m][n][r2] + bv;
          if (EPI == 1) v = fmaxf(v, 0.f);
          if constexpr (__is_same(OutT, float)) {
            C[(size_t)row * N + col] = v;
          } else {
            C[(size_t)row * N + col] = f2bf(v);
          }
        }
      }
    }
  }
}

// ---------------- build h_in = concat([ctx, x], axis=1) -> bf16 --------------
__global__ __launch_bounds__(256) void build_hin(const float* __restrict__ x,
                                                 const float* __restrict__ ctx,
                                                 short* __restrict__ hin) {
  const int r = blockIdx.x;
  const int b = r / SEQ, t = r % SEQ;
  const float* src = (t == 0) ? (ctx + (size_t)b * IN_DIM)
                              : (x + ((size_t)b * S_ + (t - 1)) * IN_DIM);
  f32x4 v = *(const f32x4*)(src + threadIdx.x * 4);
  u16x4 o;
  o.x = (unsigned short)f2bf(v.x); o.y = (unsigned short)f2bf(v.y);
  o.z = (unsigned short)f2bf(v.z); o.w = (unsigned short)f2bf(v.w);
  *(u16x4*)(hin + (size_t)r * IN_DIM + threadIdx.x * 4) = o;
}

// ---------------- attention over batch axis (32) at each (pos t, head) ------
__global__ __launch_bounds__(128) void attention_kern(const short* __restrict__ qkv,
                                                      short* __restrict__ o) {
  __shared__ alignas(16) float qs[32][132], ksm[32][132], vs[32][132];
  __shared__ float ps[32][33];
  const int t = blockIdx.x, hd = blockIdx.y, tid = threadIdx.x;
  for (int i = tid; i < 32 * 16; i += 128) {   // 32 rows x 16 chunks of 8 bf16
    const int bb = i >> 4, d8 = (i & 15) << 3;
    const size_t base = (size_t)(bb * SEQ + t) * (3 * HD) + hd * DH + d8;
    s16x8 q8 = *(const s16x8*)(qkv + base);
    s16x8 k8 = *(const s16x8*)(qkv + base + HD);
    s16x8 v8 = *(const s16x8*)(qkv + base + 2 * HD);
#pragma unroll
    for (int j = 0; j < 8; ++j) {
      qs[bb][d8 + j] = bf2f(q8[j]);
      ksm[bb][d8 + j] = bf2f(k8[j]);
      vs[bb][d8 + j] = bf2f(v8[j]);
    }
  }
  __syncthreads();
  const float scale = 0.08838834764831845f;   // 1/sqrt(128)
  for (int idx = tid; idx < 1024; idx += 128) {
    const int i = idx >> 5, j = idx & 31;
    float s = 0.f;
#pragma unroll 8
    for (int d = 0; d < DH; ++d) s += qs[i][d] * ksm[j][d];
    ps[i][j] = s * scale;
  }
  __syncthreads();
  if (tid < 32) {
    float mx = -1e30f;
#pragma unroll
    for (int j = 0; j < 32; ++j) mx = fmaxf(mx, ps[tid][j]);
    float sum = 0.f;
#pragma unroll
    for (int j = 0; j < 32; ++j) { float e = __expf(ps[tid][j] - mx); ps[tid][j] = e; sum += e; }
    const float inv = 1.f / sum;
#pragma unroll
    for (int j = 0; j < 32; ++j) ps[tid][j] *= inv;
  }
  __syncthreads();
  for (int idx = tid; idx < 32 * DH; idx += 128) {
    const int i = idx >> 7, d = idx & 127;
    float s = 0.f;
#pragma unroll
    for (int j = 0; j < 32; ++j) s += ps[i][j] * vs[j][d];
    o[(size_t)(i * SEQ + t) * HD + hd * DH + d] = f2bf(s);
  }
}

// ---------------- y = LN(h + delta) * g + b  (bf16 in / bf16 out) -----------
__global__ __launch_bounds__(256) void add_ln(const short* __restrict__ hin,
                                              const short* __restrict__ delta,
                                              const float* __restrict__ g,
                                              const float* __restrict__ bb,
                                              short* __restrict__ hout) {
  const int r = blockIdx.x, tid = threadIdx.x;
  const u16x4 hv = *(const u16x4*)(hin + (size_t)r * HD + tid * 4);
  const u16x4 dv = *(const u16x4*)(delta + (size_t)r * HD + tid * 4);
  float s0 = bf2f((short)hv.x) + bf2f((short)dv.x);
  float s1 = bf2f((short)hv.y) + bf2f((short)dv.y);
  float s2 = bf2f((short)hv.z) + bf2f((short)dv.z);
  float s3 = bf2f((short)hv.w) + bf2f((short)dv.w);
  float ls = s0 + s1 + s2 + s3;
  float l2 = s0 * s0 + s1 * s1 + s2 * s2 + s3 * s3;
#pragma unroll
  for (int off = 32; off > 0; off >>= 1) {
    ls += __shfl_down(ls, off);
    l2 += __shfl_down(l2, off);
  }
  __shared__ float red[8];
  const int wave = tid >> 6, lane = tid & 63;
  if (lane == 0) { red[wave * 2] = ls; red[wave * 2 + 1] = l2; }
  __syncthreads();
  if (tid == 0) {
    float a = 0.f, b2 = 0.f;
    for (int w = 0; w < 4; ++w) { a += red[w * 2]; b2 += red[w * 2 + 1]; }
    red[0] = a; red[1] = b2;
  }
  __syncthreads();
  const float mean = red[0] * (1.f / HD);
  const float var  = red[1] * (1.f / HD) - mean * mean;
  const float inv  = rsqrtf(var + 1e-5f);
  const f32x4 gv = *(const f32x4*)(g + tid * 4);
  const f32x4 bv = *(const f32x4*)(bb + tid * 4);
  u16x4 y;
  y.x = (unsigned short)f2bf((s0 - mean) * inv * gv.x + bv.x);
  y.y = (unsigned short)f2bf((s1 - mean) * inv * gv.y + bv.y);
  y.z = (unsigned short)f2bf((s2 - mean) * inv * gv.z + bv.z);
  y.w = (unsigned short)f2bf((s3 - mean) * inv * gv.w + bv.w);
  *(u16x4*)(hout + (size_t)r * HD + tid * 4) = y;
}

// ---- pred write + gather cand + cand_out[..,1:] + dbuf = bf16(cand-pred) ----
__global__ __launch_bounds__(256) void gather_cand(const float* __restrict__ outb,
                                                   const int* __restrict__ indices,
                                                   const float* __restrict__ KB,
                                                   float* __restrict__ pred,
                                                   float* __restrict__ cand_out,
                                                   short* __restrict__ dbuf) {
  const int bs = blockIdx.x;
  const int b = bs >> 7, s = bs & 127;
  const int c = threadIdx.x;
  const float p = outb[((size_t)b * SEQ + s + 1) * OUT_DIM + c];
  pred[(size_t)bs * OUT_DIM + c] = p;
  const int* idxp = indices + (size_t)bs * KC;
  for (int k = 0; k < KC; ++k) {
    int idx = idxp[k];
    if (idx < 0) idx = 0;
    const float cv = KB[(size_t)idx * OUT_DIM + c];
    const size_t row = (size_t)bs * KC + k;
    cand_out[row * 257 + 1 + c] = cv;
    dbuf[row * OUT_DIM + c] = f2bf(cv - p);
  }
}

// ---------------- ds = t1(bf16, relu'd) . W2 + b2 -> cand_out[row*257] ------
__global__ __launch_bounds__(256) void score_reduce(const short* __restrict__ t1,
                                                    const float* __restrict__ W2,
                                                    const float* __restrict__ b2,
                                                    float* __restrict__ cand_out) {
  const int wave = threadIdx.x >> 6, lane = threadIdx.x & 63;
  const size_t row = (size_t)blockIdx.x * 4 + wave;
  const short* tp = t1 + row * OUT_DIM;
  float sum = 0.f;
  for (int c = lane; c < OUT_DIM; c += 64) sum += bf2f(tp[c]) * W2[c];
#pragma unroll
  for (int off = 32; off > 0; off >>= 1) sum += __shfl_down(sum, off);
  if (lane == 0) cand_out[row * 257] = sum + b2[0];
}

extern "C" void kernel_launch(void* const* d_in, const int* in_sizes, int n_in,
                              void* d_out, int out_size, void* d_ws, size_t ws_size,
                              hipStream_t stream) {
  const float* x      = (const float*)d_in[0];
  const float* ctx    = (const float*)d_in[1];
  const int*   indices= (const int*)d_in[2];
  const float* KB     = (const float*)d_in[3];
  const float* W_in   = (const float*)d_in[4];
  const float* b_in   = (const float*)d_in[5];
  const float* Wqkv   = (const float*)d_in[6];
  const float* bqkv   = (const float*)d_in[7];
  const float* Wo     = (const float*)d_in[8];
  const float* bo     = (const float*)d_in[9];
  const float* ln1_g  = (const float*)d_in[10];
  const float* ln1_b  = (const float*)d_in[11];
  const float* W1     = (const float*)d_in[12];
  const float* b1     = (const float*)d_in[13];
  const float* W2     = (const float*)d_in[14];
  const float* b2     = (const float*)d_in[15];
  const float* ln2_g  = (const float*)d_in[16];
  const float* ln2_b  = (const float*)d_in[17];
  const float* W_out  = (const float*)d_in[18];
  const float* b_out  = (const float*)d_in[19];
  const float* ds_W1  = (const float*)d_in[20];
  const float* ds_b1  = (const float*)d_in[21];
  const float* ds_W2  = (const float*)d_in[22];
  const float* ds_b2  = (const float*)d_in[23];
  // d_in[24..27] = cs_* : dead code in reference (del cs)

  char* p = (char*)d_ws;
  auto alloc = [&](size_t bytes) {
    char* q = p;
    p += (bytes + 255) & ~(size_t)255;
    return q;
  };
  short* h    = (short*)alloc((size_t)MPAD * HD * 2);
  short* tmp1 = (short*)alloc((size_t)MPAD * 3 * HD * 2);  // qkv / ff1
  short* tmp2 = (short*)alloc((size_t)MPAD * HD * 2);      // hin / attn-o
  short* tmp3 = (short*)alloc((size_t)MPAD * HD * 2);      // Wo out / ff2
  float* outb = (float*)alloc((size_t)MROWS * OUT_DIM * 4);
  short* dbuf = (short*)alloc((size_t)NCAND * OUT_DIM * 2);
  short* t1   = (short*)alloc((size_t)NCAND * OUT_DIM * 2);
  short* WinT  = (short*)alloc((size_t)HD * IN_DIM * 2);
  short* WqkvT = (short*)alloc((size_t)2 * 3 * HD * HD * 2);
  short* WoT   = (short*)alloc((size_t)2 * HD * HD * 2);
  short* W1T   = (short*)alloc((size_t)2 * DFF * HD * 2);
  short* W2T   = (short*)alloc((size_t)2 * HD * DFF * 2);
  short* WoutT = (short*)alloc((size_t)OUT_DIM * HD * 2);
  short* dsW1T = (short*)alloc((size_t)OUT_DIM * OUT_DIM * 2);

  // all weight transposes (f32 -> bf16, N x K) in ONE dispatch
  transpose_all<<<17728, 256, 0, stream>>>(W_in, Wqkv, Wo, W1, W2, W_out, ds_W1,
                                           WinT, WqkvT, WoT, W1T, W2T, WoutT, dsW1T);

  // forward
  build_hin<<<MROWS, 256, 0, stream>>>(x, ctx, tmp2);
  gemm_bt<1, short><<<33 * 8, 256, 0, stream>>>(tmp2, WinT, b_in, h,
                                                MROWS, 1024, 1024, 33, 8, 8);

  for (int l = 0; l < 2; ++l) {
    gemm_bt<0, short><<<33 * 24, 256, 0, stream>>>(
        h, WqkvT + (size_t)l * 3072 * 1024, bqkv + l * 3072, tmp1,
        MROWS, 3072, 1024, 33, 24, 8);
    attention_kern<<<dim3(SEQ, NHEAD), 128, 0, stream>>>(tmp1, tmp2);
    gemm_bt<0, short><<<33 * 8, 256, 0, stream>>>(
        tmp2, WoT + (size_t)l * 1024 * 1024, bo + l * 1024, tmp3,
        MROWS, 1024, 1024, 33, 8, 8);
    add_ln<<<MROWS, 256, 0, stream>>>(h, tmp3, ln1_g + l * 1024, ln1_b + l * 1024, h);
    gemm_bt<1, short><<<33 * 16, 256, 0, stream>>>(
        h, W1T + (size_t)l * 2048 * 1024, b1 + l * 2048, tmp1,
        MROWS, 2048, 1024, 33, 16, 8);
    gemm_bt<0, short><<<33 * 8, 256, 0, stream>>>(
        tmp1, W2T + (size_t)l * 1024 * 2048, b2 + l * 1024, tmp3,
        MROWS, 1024, 2048, 33, 8, 4);
    add_ln<<<MROWS, 256, 0, stream>>>(h, tmp3, ln2_g + l * 1024, ln2_b + l * 1024, h);
  }

  gemm_bt<0, float><<<33 * 2, 256, 0, stream>>>(h, WoutT, b_out, outb,
                                                MROWS, 256, 1024, 33, 2, 8);

  float* pred = (float*)d_out;
  float* cand_out = (float*)d_out + (size_t)B_ * S_ * OUT_DIM;
  gather_cand<<<4096, 256, 0, stream>>>(outb, indices, KB, pred, cand_out, dbuf);
  gemm_bt<1, short><<<320 * 2, 256, 0, stream>>>(dbuf, dsW1T, ds_b1, t1,
                                                 NCAND, 256, 256, 320, 2, 16);
  score_reduce<<<NCAND / 4, 256, 0, stream>>>(t1, ds_W2, ds_b2, cand_out);
}